// Round 4
// baseline (283.558 us; speedup 1.0000x reference)
//
#include <hip/hip_runtime.h>

// GAN hinge loss reduction:
//   contrib = (t==+1) ? min(0, D-1) : (t==-1) ? min(0, -1-D) : 0
//   out[0]  = sum(contrib) / N
// N = 33554432 (2^25), fp32 scores + int32 targets -> fp32 scalar.
// Memory-bound: 256 MiB read, 4 B write. Roofline ~43 us at 6.3 TB/s.
//
// Branch-free form: for t in {-1,+1}, t*(D - t) equals (D-1) for t=+1 and
// -(1+D) for t=-1, so contrib = min(0, t*(D-t)) masked by (t*t==1).

__global__ __launch_bounds__(256) void ganloss_kernel(
    const float* __restrict__ D, const int* __restrict__ T,
    float* __restrict__ out, int n4, float inv_n) {
  const float4* __restrict__ D4 = reinterpret_cast<const float4*>(D);
  const int4* __restrict__ T4 = reinterpret_cast<const int4*>(T);

  int tid = blockIdx.x * blockDim.x + threadIdx.x;
  int stride = gridDim.x * blockDim.x;

  float acc = 0.0f;
  for (int i = tid; i < n4; i += stride) {
    float4 d = D4[i];
    int4 t = T4[i];
    float tf0 = (float)t.x, tf1 = (float)t.y, tf2 = (float)t.z, tf3 = (float)t.w;
    float c0 = (t.x * t.x == 1) ? fminf(0.0f, tf0 * (d.x - tf0)) : 0.0f;
    float c1 = (t.y * t.y == 1) ? fminf(0.0f, tf1 * (d.y - tf1)) : 0.0f;
    float c2 = (t.z * t.z == 1) ? fminf(0.0f, tf2 * (d.z - tf2)) : 0.0f;
    float c3 = (t.w * t.w == 1) ? fminf(0.0f, tf3 * (d.w - tf3)) : 0.0f;
    acc += (c0 + c1) + (c2 + c3);
  }

  // wave-64 butterfly reduce
  #pragma unroll
  for (int off = 32; off > 0; off >>= 1)
    acc += __shfl_down(acc, off, 64);

  __shared__ float wsum[4];  // 256 threads = 4 waves
  int lane = threadIdx.x & 63;
  int wid = threadIdx.x >> 6;
  if (lane == 0) wsum[wid] = acc;
  __syncthreads();

  if (threadIdx.x == 0) {
    float s = (wsum[0] + wsum[1]) + (wsum[2] + wsum[3]);
    atomicAdd(out, s * inv_n);  // device-scope by default on CDNA
  }
}

extern "C" void kernel_launch(void* const* d_in, const int* in_sizes, int n_in,
                              void* d_out, int out_size, void* d_ws, size_t ws_size,
                              hipStream_t stream) {
  const float* D = (const float*)d_in[0];
  const int* T = (const int*)d_in[1];
  float* out = (float*)d_out;
  int n = in_sizes[0];       // 33554432, divisible by 4*256*2048
  int n4 = n >> 2;
  float inv_n = 1.0f / (float)n;

  // d_out is poisoned to 0xAA before every timed replay -> zero it here.
  hipMemsetAsync(d_out, 0, out_size * sizeof(float), stream);

  const int block = 256;
  int grid = 2048;  // ~8 blocks/CU; grid-stride covers the rest (16 it/thread)
  ganloss_kernel<<<grid, block, 0, stream>>>(D, T, out, n4, inv_n);
}

// Round 6
// 280.399 us; speedup vs baseline: 1.0113x; 1.0113x over previous
//
#include <hip/hip_runtime.h>

// GAN hinge loss reduction:
//   contrib = (t==+1) ? min(0, D-1) : (t==-1) ? min(0, -1-D) : 0
//   out[0]  = sum(contrib) / N
// N = 33554432 (2^25), fp32 scores + int32 targets -> fp32 scalar.
// Memory-bound: 256 MiB read. R4 measured 108 us (2.48 TB/s effective,
// VALUBusy 7%) -> MLP-limited, not BW-limited. This version batches 8
// independent 16B loads per wave-iteration (8 KB in flight/wave, 4x R4).
//
// Math: for t in {-1,+1}, t*(D-t) = t*D - 1, so contrib = min(0, t*D - 1),
// masked by (t*t==1) to preserve exact reference semantics for other t.

#define UNROLL 4

__device__ __forceinline__ float chunk_contrib(float4 d, int4 t) {
  float c0 = (t.x * t.x == 1) ? fminf(0.0f, __fmaf_rn((float)t.x, d.x, -1.0f)) : 0.0f;
  float c1 = (t.y * t.y == 1) ? fminf(0.0f, __fmaf_rn((float)t.y, d.y, -1.0f)) : 0.0f;
  float c2 = (t.z * t.z == 1) ? fminf(0.0f, __fmaf_rn((float)t.z, d.z, -1.0f)) : 0.0f;
  float c3 = (t.w * t.w == 1) ? fminf(0.0f, __fmaf_rn((float)t.w, d.w, -1.0f)) : 0.0f;
  return (c0 + c1) + (c2 + c3);
}

__global__ __launch_bounds__(256) void ganloss_kernel(
    const float* __restrict__ D, const int* __restrict__ T,
    float* __restrict__ out, int n4, float inv_n) {
  const float4* __restrict__ D4 = reinterpret_cast<const float4*>(D);
  const int4* __restrict__ T4 = reinterpret_cast<const int4*>(T);

  int tid = blockIdx.x * blockDim.x + threadIdx.x;
  int s = gridDim.x * blockDim.x;

  float acc = 0.0f;
  int i = tid;
  // main loop: 8 independent loads issued before any consumption
  for (; i + 3 * s < n4; i += UNROLL * s) {
    float4 d0 = D4[i];
    float4 d1 = D4[i + s];
    float4 d2 = D4[i + 2 * s];
    float4 d3 = D4[i + 3 * s];
    int4 t0 = T4[i];
    int4 t1 = T4[i + s];
    int4 t2 = T4[i + 2 * s];
    int4 t3 = T4[i + 3 * s];
    acc += chunk_contrib(d0, t0);
    acc += chunk_contrib(d1, t1);
    acc += chunk_contrib(d2, t2);
    acc += chunk_contrib(d3, t3);
  }
  // tail (never taken for N=2^25 with grid 2048x256, kept for generality)
  for (; i < n4; i += s) acc += chunk_contrib(D4[i], T4[i]);

  // wave-64 butterfly reduce
  #pragma unroll
  for (int off = 32; off > 0; off >>= 1)
    acc += __shfl_down(acc, off, 64);

  __shared__ float wsum[4];  // 256 threads = 4 waves
  int lane = threadIdx.x & 63;
  int wid = threadIdx.x >> 6;
  if (lane == 0) wsum[wid] = acc;
  __syncthreads();

  if (threadIdx.x == 0) {
    float ssum = (wsum[0] + wsum[1]) + (wsum[2] + wsum[3]);
    atomicAdd(out, ssum * inv_n);  // device-scope by default on CDNA
  }
}

extern "C" void kernel_launch(void* const* d_in, const int* in_sizes, int n_in,
                              void* d_out, int out_size, void* d_ws, size_t ws_size,
                              hipStream_t stream) {
  const float* D = (const float*)d_in[0];
  const int* T = (const int*)d_in[1];
  float* out = (float*)d_out;
  int n = in_sizes[0];       // 33554432
  int n4 = n >> 2;           // 8388608 float4/int4 chunks
  float inv_n = 1.0f / (float)n;

  // d_out is poisoned to 0xAA before every timed replay -> zero it here.
  hipMemsetAsync(d_out, 0, out_size * sizeof(float), stream);

  const int block = 256;
  int grid = 2048;  // 8 blocks/CU; 16 chunks/thread = 4 unrolled iterations
  ganloss_kernel<<<grid, block, 0, stream>>>(D, T, out, n4, inv_n);
}

// Round 7
// 274.852 us; speedup vs baseline: 1.0317x; 1.0202x over previous
//
#include <hip/hip_runtime.h>

// GAN hinge loss reduction, two-stage (no global atomics):
//   contrib = (t==+1) ? min(0, D-1) : (t==-1) ? min(0, -1-D) : 0
//   out[0]  = sum(contrib) / N
// N = 2^25, fp32 + int32 -> fp32 scalar. 256 MiB read, memory-bound.
//
// R4/R6 post-mortem: 110 us regardless of MLP depth, VALU idle, avg BW
// 2.4 TB/s. Hypothesis: uniform work => all 2048 blocks finish together =>
// 2048 same-address device-scope atomicAdds serialize as a pure tail.
// This version writes per-block partials to d_ws; a 1-block kernel reduces.
//
// Math: for t in {-1,+1}, t*(D-t) = t*D - 1 => contrib = min(0, t*D - 1),
// masked by (t*t==1) to preserve exact reference semantics for other t.

__global__ __launch_bounds__(256) void ganloss_partial(
    const float* __restrict__ D, const int* __restrict__ T,
    float* __restrict__ partials, int n4) {
  const float4* __restrict__ D4 = reinterpret_cast<const float4*>(D);
  const int4* __restrict__ T4 = reinterpret_cast<const int4*>(T);

  int tid = blockIdx.x * blockDim.x + threadIdx.x;
  int stride = gridDim.x * blockDim.x;

  float acc = 0.0f;
  for (int i = tid; i < n4; i += stride) {
    float4 d = D4[i];
    int4 t = T4[i];
    float c0 = (t.x * t.x == 1) ? fminf(0.0f, __fmaf_rn((float)t.x, d.x, -1.0f)) : 0.0f;
    float c1 = (t.y * t.y == 1) ? fminf(0.0f, __fmaf_rn((float)t.y, d.y, -1.0f)) : 0.0f;
    float c2 = (t.z * t.z == 1) ? fminf(0.0f, __fmaf_rn((float)t.z, d.z, -1.0f)) : 0.0f;
    float c3 = (t.w * t.w == 1) ? fminf(0.0f, __fmaf_rn((float)t.w, d.w, -1.0f)) : 0.0f;
    acc += (c0 + c1) + (c2 + c3);
  }

  // wave-64 butterfly reduce
  #pragma unroll
  for (int off = 32; off > 0; off >>= 1)
    acc += __shfl_down(acc, off, 64);

  __shared__ float wsum[4];  // 256 threads = 4 waves
  int lane = threadIdx.x & 63;
  int wid = threadIdx.x >> 6;
  if (lane == 0) wsum[wid] = acc;
  __syncthreads();

  if (threadIdx.x == 0)
    partials[blockIdx.x] = (wsum[0] + wsum[1]) + (wsum[2] + wsum[3]);
}

__global__ __launch_bounds__(256) void ganloss_final(
    const float* __restrict__ partials, float* __restrict__ out,
    int nparts, float inv_n) {
  float acc = 0.0f;
  for (int i = threadIdx.x; i < nparts; i += 256)
    acc += partials[i];

  #pragma unroll
  for (int off = 32; off > 0; off >>= 1)
    acc += __shfl_down(acc, off, 64);

  __shared__ float wsum[4];
  int lane = threadIdx.x & 63;
  int wid = threadIdx.x >> 6;
  if (lane == 0) wsum[wid] = acc;
  __syncthreads();

  if (threadIdx.x == 0)
    out[0] = ((wsum[0] + wsum[1]) + (wsum[2] + wsum[3])) * inv_n;
}

extern "C" void kernel_launch(void* const* d_in, const int* in_sizes, int n_in,
                              void* d_out, int out_size, void* d_ws, size_t ws_size,
                              hipStream_t stream) {
  const float* D = (const float*)d_in[0];
  const int* T = (const int*)d_in[1];
  float* out = (float*)d_out;
  float* partials = (float*)d_ws;  // 2048 * 4 B = 8 KB scratch
  int n = in_sizes[0];             // 33554432
  int n4 = n >> 2;                 // 8388608 float4/int4 chunks
  float inv_n = 1.0f / (float)n;

  const int block = 256;
  const int grid = 2048;  // 8 blocks/CU; 16 chunks/thread via grid-stride

  ganloss_partial<<<grid, block, 0, stream>>>(D, T, partials, n4);
  // same-stream ordering makes partials visible; out[0] written
  // unconditionally (no memset of the poisoned d_out needed).
  ganloss_final<<<1, block, 0, stream>>>(partials, out, grid, inv_n);
}

// Round 9
// 248.110 us; speedup vs baseline: 1.1429x; 1.1078x over previous
//
#include <hip/hip_runtime.h>

// GAN hinge loss reduction, two-stage (no global atomics):
//   contrib = (t==+1) ? min(0, D-1) : (t==-1) ? min(0, -1-D) : 0
//   out[0]  = sum(contrib) / N
// N = 2^25, fp32 + int32 -> fp32 scalar. 268 MB read, memory-bound.
//
// History: R4 110us (atomic tail), R6 unroll null, R7 partials 96us
// (2.8 TB/s delivered; known-good streaming kernels hit ~5 TB/s here).
// This version: per-wave 2KB-contiguous bursts per stream (wave owns 128
// consecutive chunks; 2 contiguous 1KB loads per stream, all 4 batched) +
// nontemporal hints. NOTE: __builtin_nontemporal_load requires clang
// ext_vector types, not HIP_vector_type structs (R8 compile failure).
//
// Math: for t in {-1,+1}, t*(D-t) = t*D - 1 => contrib = min(0, t*D - 1),
// masked by (t*t==1) to preserve exact reference semantics for other t.

typedef float  vfloat4 __attribute__((ext_vector_type(4)));
typedef int    vint4   __attribute__((ext_vector_type(4)));

__device__ __forceinline__ float chunk_contrib(vfloat4 d, vint4 t) {
  float c0 = (t.x * t.x == 1) ? fminf(0.0f, __fmaf_rn((float)t.x, d.x, -1.0f)) : 0.0f;
  float c1 = (t.y * t.y == 1) ? fminf(0.0f, __fmaf_rn((float)t.y, d.y, -1.0f)) : 0.0f;
  float c2 = (t.z * t.z == 1) ? fminf(0.0f, __fmaf_rn((float)t.z, d.z, -1.0f)) : 0.0f;
  float c3 = (t.w * t.w == 1) ? fminf(0.0f, __fmaf_rn((float)t.w, d.w, -1.0f)) : 0.0f;
  return (c0 + c1) + (c2 + c3);
}

__global__ __launch_bounds__(256) void ganloss_partial(
    const float* __restrict__ D, const int* __restrict__ T,
    float* __restrict__ partials, int n4) {
  const vfloat4* __restrict__ D4 = reinterpret_cast<const vfloat4*>(D);
  const vint4* __restrict__ T4 = reinterpret_cast<const vint4*>(T);

  int lane = threadIdx.x & 63;
  int wid = threadIdx.x >> 6;
  int gwave = blockIdx.x * 4 + wid;          // global wave id
  int nwaves = gridDim.x * 4;                 // 8192 waves
  // each wave owns 128 consecutive chunks per iteration: 2KB contiguous/stream

  float acc = 0.0f;
  for (int k = gwave; k * 128 < n4; k += nwaves) {
    int base = k * 128;
    // batch all 4 loads (2 per stream, each 1KB contiguous across the wave)
    vfloat4 d0 = __builtin_nontemporal_load(&D4[base + lane]);
    vfloat4 d1 = __builtin_nontemporal_load(&D4[base + 64 + lane]);
    vint4 t0 = __builtin_nontemporal_load(&T4[base + lane]);
    vint4 t1 = __builtin_nontemporal_load(&T4[base + 64 + lane]);
    acc += chunk_contrib(d0, t0);
    acc += chunk_contrib(d1, t1);
  }

  // wave-64 butterfly reduce
  #pragma unroll
  for (int off = 32; off > 0; off >>= 1)
    acc += __shfl_down(acc, off, 64);

  __shared__ float wsum[4];  // 256 threads = 4 waves
  if (lane == 0) wsum[wid] = acc;
  __syncthreads();

  if (threadIdx.x == 0)
    partials[blockIdx.x] = (wsum[0] + wsum[1]) + (wsum[2] + wsum[3]);
}

__global__ __launch_bounds__(256) void ganloss_final(
    const float* __restrict__ partials, float* __restrict__ out,
    int nparts, float inv_n) {
  float acc = 0.0f;
  for (int i = threadIdx.x; i < nparts; i += 256)
    acc += partials[i];

  #pragma unroll
  for (int off = 32; off > 0; off >>= 1)
    acc += __shfl_down(acc, off, 64);

  __shared__ float wsum[4];
  int lane = threadIdx.x & 63;
  int wid = threadIdx.x >> 6;
  if (lane == 0) wsum[wid] = acc;
  __syncthreads();

  if (threadIdx.x == 0)
    out[0] = ((wsum[0] + wsum[1]) + (wsum[2] + wsum[3])) * inv_n;
}

extern "C" void kernel_launch(void* const* d_in, const int* in_sizes, int n_in,
                              void* d_out, int out_size, void* d_ws, size_t ws_size,
                              hipStream_t stream) {
  const float* D = (const float*)d_in[0];
  const int* T = (const int*)d_in[1];
  float* out = (float*)d_out;
  float* partials = (float*)d_ws;  // 2048 * 4 B = 8 KB scratch
  int n = in_sizes[0];             // 33554432
  int n4 = n >> 2;                 // 8388608 chunks
  float inv_n = 1.0f / (float)n;

  const int block = 256;
  const int grid = 2048;  // 8192 waves; 8 iterations of 128 chunks each

  ganloss_partial<<<grid, block, 0, stream>>>(D, T, partials, n4);
  // same-stream ordering makes partials visible; out[0] written
  // unconditionally (no memset of the poisoned d_out needed).
  ganloss_final<<<1, block, 0, stream>>>(partials, out, grid, inv_n);
}

// Round 13
// 247.542 us; speedup vs baseline: 1.1455x; 1.0023x over previous
//
#include <hip/hip_runtime.h>

// GAN hinge loss reduction, two-stage (no global atomics):
//   contrib = (t==+1) ? min(0, D-1) : (t==-1) ? min(0, -1-D) : 0
//   out[0]  = sum(contrib) / N
// N = 2^25, fp32 + int32 -> fp32 scalar. 268 MB read, memory-bound.
//
// History: R4 110us (atomic tail) -> R7 96us (partials, no atomic) ->
// R9 <77us (NT loads + 2KB/wave contiguous bursts; kernel fell out of
// rocprof top-5, which is now harness poison-fills at 6.9 TB/s).
// This version: double the burst -> 8 NT loads in flight per iteration
// (wave owns 256 consecutive chunks; 4KB contiguous per stream), halving
// the load->consume round-trips. R6's unroll-null was the strided pattern
// pre-NT/pre-atomic-fix -- different regime, doesn't contradict.
//
// Math: for t in {-1,+1}, t*(D-t) = t*D - 1 => contrib = min(0, t*D - 1),
// masked by (t*t==1) to preserve exact reference semantics for other t.

typedef float  vfloat4 __attribute__((ext_vector_type(4)));
typedef int    vint4   __attribute__((ext_vector_type(4)));

__device__ __forceinline__ float chunk_contrib(vfloat4 d, vint4 t) {
  float c0 = (t.x * t.x == 1) ? fminf(0.0f, __fmaf_rn((float)t.x, d.x, -1.0f)) : 0.0f;
  float c1 = (t.y * t.y == 1) ? fminf(0.0f, __fmaf_rn((float)t.y, d.y, -1.0f)) : 0.0f;
  float c2 = (t.z * t.z == 1) ? fminf(0.0f, __fmaf_rn((float)t.z, d.z, -1.0f)) : 0.0f;
  float c3 = (t.w * t.w == 1) ? fminf(0.0f, __fmaf_rn((float)t.w, d.w, -1.0f)) : 0.0f;
  return (c0 + c1) + (c2 + c3);
}

__global__ __launch_bounds__(256) void ganloss_partial(
    const float* __restrict__ D, const int* __restrict__ T,
    float* __restrict__ partials, int n4) {
  const vfloat4* __restrict__ D4 = reinterpret_cast<const vfloat4*>(D);
  const vint4* __restrict__ T4 = reinterpret_cast<const vint4*>(T);

  int lane = threadIdx.x & 63;
  int wid = threadIdx.x >> 6;
  int gwave = blockIdx.x * 4 + wid;          // global wave id
  int nwaves = gridDim.x * 4;                 // 8192 waves
  // each wave owns 256 consecutive chunks per iteration:
  // 4KB contiguous per stream, 8 NT loads issued before any consume.

  float acc = 0.0f;
  for (int k = gwave; k * 256 < n4; k += nwaves) {
    int base = k * 256;
    vfloat4 d0 = __builtin_nontemporal_load(&D4[base + lane]);
    vfloat4 d1 = __builtin_nontemporal_load(&D4[base + 64 + lane]);
    vfloat4 d2 = __builtin_nontemporal_load(&D4[base + 128 + lane]);
    vfloat4 d3 = __builtin_nontemporal_load(&D4[base + 192 + lane]);
    vint4 t0 = __builtin_nontemporal_load(&T4[base + lane]);
    vint4 t1 = __builtin_nontemporal_load(&T4[base + 64 + lane]);
    vint4 t2 = __builtin_nontemporal_load(&T4[base + 128 + lane]);
    vint4 t3 = __builtin_nontemporal_load(&T4[base + 192 + lane]);
    acc += chunk_contrib(d0, t0);
    acc += chunk_contrib(d1, t1);
    acc += chunk_contrib(d2, t2);
    acc += chunk_contrib(d3, t3);
  }

  // wave-64 butterfly reduce
  #pragma unroll
  for (int off = 32; off > 0; off >>= 1)
    acc += __shfl_down(acc, off, 64);

  __shared__ float wsum[4];  // 256 threads = 4 waves
  if (lane == 0) wsum[wid] = acc;
  __syncthreads();

  if (threadIdx.x == 0)
    partials[blockIdx.x] = (wsum[0] + wsum[1]) + (wsum[2] + wsum[3]);
}

__global__ __launch_bounds__(256) void ganloss_final(
    const float* __restrict__ partials, float* __restrict__ out,
    int nparts, float inv_n) {
  float acc = 0.0f;
  for (int i = threadIdx.x; i < nparts; i += 256)
    acc += partials[i];

  #pragma unroll
  for (int off = 32; off > 0; off >>= 1)
    acc += __shfl_down(acc, off, 64);

  __shared__ float wsum[4];
  int lane = threadIdx.x & 63;
  int wid = threadIdx.x >> 6;
  if (lane == 0) wsum[wid] = acc;
  __syncthreads();

  if (threadIdx.x == 0)
    out[0] = ((wsum[0] + wsum[1]) + (wsum[2] + wsum[3])) * inv_n;
}

extern "C" void kernel_launch(void* const* d_in, const int* in_sizes, int n_in,
                              void* d_out, int out_size, void* d_ws, size_t ws_size,
                              hipStream_t stream) {
  const float* D = (const float*)d_in[0];
  const int* T = (const int*)d_in[1];
  float* out = (float*)d_out;
  float* partials = (float*)d_ws;  // 2048 * 4 B = 8 KB scratch
  int n = in_sizes[0];             // 33554432
  int n4 = n >> 2;                 // 8388608 chunks
  float inv_n = 1.0f / (float)n;

  const int block = 256;
  const int grid = 2048;  // 8192 waves; 4 iterations of 256 chunks each

  ganloss_partial<<<grid, block, 0, stream>>>(D, T, partials, n4);
  // same-stream ordering makes partials visible; out[0] written
  // unconditionally (no memset of the poisoned d_out needed).
  ganloss_final<<<1, block, 0, stream>>>(partials, out, grid, inv_n);
}